// Round 1
// baseline (587.549 us; speedup 1.0000x reference)
//
#include <hip/hip_runtime.h>

using bf16x8 = __attribute__((ext_vector_type(8))) short;
using f32x4  = __attribute__((ext_vector_type(4))) float;

#define B_  2
#define T_  2048
#define C_  2048
#define H_  16
#define KV_ 4
#define D_  128

__device__ __forceinline__ unsigned short f2b(float f) {
  union { float f; unsigned int u; } v; v.f = f;
  unsigned int r = v.u + 0x7fffu + ((v.u >> 16) & 1u);   // RTNE
  return (unsigned short)(r >> 16);
}
__device__ __forceinline__ float b2f(unsigned short u) {
  union { unsigned int u; float f; } v; v.u = ((unsigned int)u) << 16;
  return v.f;
}
// async global->LDS, 16B per lane; LDS dest must be lane-contiguous (wave base + lane*16)
__device__ __forceinline__ void gld_lds16(const void* g, void* l) {
  __builtin_amdgcn_global_load_lds(
      (__attribute__((address_space(1))) void*)g,
      (__attribute__((address_space(3))) void*)l, 16, 0, 0);
}

// ---------------- elementwise cast x -> bf16 ----------------
__global__ void cast_bf16_k(const float* __restrict__ in, unsigned short* __restrict__ out) {
  int i = blockIdx.x * 256 + threadIdx.x;
  float4 f = ((const float4*)in)[i];
  ushort4 u; u.x = f2b(f.x); u.y = f2b(f.y); u.z = f2b(f.z); u.w = f2b(f.w);
  ((ushort4*)out)[i] = u;
}

// ---------------- transpose-cast W (K x N fp32) -> Wt (N x K bf16) ----------------
__global__ void wtrans(const float* __restrict__ W, unsigned short* __restrict__ Wt,
                       int K, int N) {
  __shared__ float s[32][33];
  int n0 = blockIdx.x * 32, k0 = blockIdx.y * 32;
  int tx = threadIdx.x, ty = threadIdx.y;
  #pragma unroll
  for (int yy = 0; yy < 32; yy += 8)
    s[ty + yy][tx] = W[(size_t)(k0 + ty + yy) * N + n0 + tx];
  __syncthreads();
  #pragma unroll
  for (int yy = 0; yy < 32; yy += 8)
    Wt[(size_t)(n0 + ty + yy) * K + k0 + tx] = f2b(s[tx][ty + yy]);
}

// ---------------- m97-style bf16 MFMA GEMM tile: C = A(MxK) * Bt(NxK)^T ----------------
template <bool OUT_BF16>
__device__ __forceinline__ void gemm_tile(
    const unsigned short* __restrict__ A, const unsigned short* __restrict__ Bt,
    void* __restrict__ Cv, int K, int ldc, int m0, int n0b, int n0c,
    unsigned short* sA, unsigned short* sB)
{
  const int tid  = threadIdx.x;
  const int lane = tid & 63, w = tid >> 6;
  const int quad = lane >> 4, l16 = lane & 15;
  const int wm = (w >> 1) * 64, wn = (w & 1) * 64;

  f32x4 acc[4][4] = {};

  const unsigned short* Abase = A  + (size_t)m0  * K;
  const unsigned short* Bbase = Bt + (size_t)n0b * K;

  for (int k0 = 0; k0 < K; k0 += 32) {
    #pragma unroll
    for (int r = 0; r < 2; ++r) {                   // 128x32 bf16 tile = 512 chunks of 16B
      int c = tid + r * 256;
      int row = c >> 2, col = (c & 3) * 8;
      gld_lds16(Abase + (size_t)row * K + k0 + col, sA + c * 8);
      gld_lds16(Bbase + (size_t)row * K + k0 + col, sB + c * 8);
    }
    __syncthreads();                                // drains vmcnt, LDS visible
    bf16x8 af[4], bfr[4];
    #pragma unroll
    for (int i = 0; i < 4; ++i)
      af[i]  = *(const bf16x8*)(sA + (wm + i * 16 + l16) * 32 + quad * 8);
    #pragma unroll
    for (int j = 0; j < 4; ++j)
      bfr[j] = *(const bf16x8*)(sB + (wn + j * 16 + l16) * 32 + quad * 8);
    #pragma unroll
    for (int i = 0; i < 4; ++i)
      #pragma unroll
      for (int j = 0; j < 4; ++j)
        acc[i][j] = __builtin_amdgcn_mfma_f32_16x16x32_bf16(af[i], bfr[j], acc[i][j], 0, 0, 0);
    __syncthreads();                                // all waves done reading before overwrite
  }
  #pragma unroll
  for (int i = 0; i < 4; ++i) {
    #pragma unroll
    for (int r = 0; r < 4; ++r) {
      int row = m0 + wm + i * 16 + quad * 4 + r;    // C/D: row = quad*4+reg, col = lane&15
      #pragma unroll
      for (int j = 0; j < 4; ++j) {
        int col = n0c + wn + j * 16 + l16;
        float v = acc[i][j][r];
        if (OUT_BF16) ((unsigned short*)Cv)[(size_t)row * ldc + col] = f2b(v);
        else          ((float*)Cv)[(size_t)row * ldc + col] = v;
      }
    }
  }
}

// fused QKV projection: 24 n-tiles (16 Q, 4 K, 4 V) x 32 m-tiles
__global__ void qkv_gemm(const unsigned short* __restrict__ xb,
                         const unsigned short* __restrict__ Wqt,
                         const unsigned short* __restrict__ Wkt,
                         const unsigned short* __restrict__ Wvt,
                         unsigned short* q, unsigned short* k, unsigned short* v) {
  __shared__ unsigned short sA[128 * 32], sB[128 * 32];
  int nt = blockIdx.x, mt = blockIdx.y;
  const unsigned short* Bt; unsigned short* C; int n0, ldc;
  if (nt < 16)      { Bt = Wqt; C = q; n0 = nt * 128;        ldc = H_ * D_;  }
  else if (nt < 20) { Bt = Wkt; C = k; n0 = (nt - 16) * 128; ldc = KV_ * D_; }
  else              { Bt = Wvt; C = v; n0 = (nt - 20) * 128; ldc = KV_ * D_; }
  gemm_tile<true>(xb, Bt, C, C_, ldc, mt * 128, n0, n0, sA, sB);
}

__global__ void out_gemm(const unsigned short* __restrict__ yb,
                         const unsigned short* __restrict__ Wot,
                         float* __restrict__ out) {
  __shared__ unsigned short sA[128 * 32], sB[128 * 32];
  gemm_tile<false>(yb, Wot, out, C_, C_, blockIdx.y * 128, blockIdx.x * 128, blockIdx.x * 128,
                   sA, sB);
}

// ---------------- RoPE + RMSNorm: one wave per (b,t,head) row of 128 ----------------
__global__ void ropenorm(const unsigned short* __restrict__ in,
                         const float* __restrict__ cs, const float* __restrict__ sn,
                         unsigned short* __restrict__ out, int NH, float oscale) {
  int row  = blockIdx.x * 4 + (threadIdx.x >> 6);
  int lane = threadIdx.x & 63;
  int t = (row / NH) & (T_ - 1);
  const unsigned short* p = in + (size_t)row * D_;
  float t1 = b2f(p[lane]), t2 = b2f(p[lane + 64]);
  float c = cs[t * 64 + lane], s = sn[t * 64 + lane];
  float o1 = t1 * c + t2 * s;
  float o2 = t2 * c - t1 * s;
  float ss = o1 * o1 + o2 * o2;
  #pragma unroll
  for (int off = 32; off > 0; off >>= 1) ss += __shfl_xor(ss, off, 64);
  float r = rsqrtf(ss * (1.0f / 128.0f) + 1.1920929e-07f) * oscale;
  unsigned short* q = out + (size_t)row * D_;
  q[lane]      = f2b(o1 * r);
  q[lane + 64] = f2b(o2 * r);
}

// ---------------- V transpose: (B,T,KV,D) bf16 -> (B,KV,D,T) bf16 ----------------
__global__ void vtrans(const unsigned short* __restrict__ v, unsigned short* __restrict__ vt) {
  __shared__ unsigned short s[32][33];
  int t0 = blockIdx.x * 32, d0 = blockIdx.y * 32;
  int bk = blockIdx.z; int b = bk >> 2, kv = bk & 3;
  int tx = threadIdx.x, ty = threadIdx.y;
  #pragma unroll
  for (int yy = 0; yy < 32; yy += 8)
    s[ty + yy][tx] = v[(((size_t)(b * T_) + t0 + ty + yy) * KV_ + kv) * D_ + d0 + tx];
  __syncthreads();
  #pragma unroll
  for (int yy = 0; yy < 32; yy += 8)
    vt[(((size_t)(b * KV_) + kv) * D_ + d0 + ty + yy) * T_ + t0 + tx] = s[tx][ty + yy];
}

// ---------------- flash attention: 128-row Q tile, 64-wide causal KV tiles ----------------
__global__ __launch_bounds__(256) void attn_kernel(
    const unsigned short* __restrict__ qb, const unsigned short* __restrict__ kb,
    const unsigned short* __restrict__ vt, unsigned short* __restrict__ yb) {
  __shared__ unsigned short sQ[128 * 128];   // 32KB
  __shared__ unsigned short sKP[64 * 128];   // 16KB: K tile, then reused for P
  __shared__ unsigned short sV[128 * 64];    // 16KB: V^T tile (rows d, cols t)

  const int qt = 15 - (int)blockIdx.x;       // heavy (late) Q tiles scheduled first
  const int q0 = qt * 128;
  const int bh = blockIdx.y;
  const int b = bh >> 4, h = bh & 15, kv = h >> 2;

  const int tid = threadIdx.x;
  const int lane = tid & 63, w = tid >> 6;
  const int quad = lane >> 4, l16 = lane & 15;
  const int wm = w * 32;                     // wave's 32 Q rows

  const unsigned short* Qg = qb + (((size_t)(b * T_ + q0)) * H_ + h) * D_;
  const unsigned short* Kg = kb + ((size_t)(b * T_) * KV_ + kv) * D_;
  const unsigned short* Vg = vt + ((size_t)(b * KV_ + kv)) * (size_t)D_ * T_;

  #pragma unroll
  for (int r = 0; r < 8; ++r) {              // Q tile: 2048 chunks of 16B
    int c = tid + r * 256;
    int row = c >> 4, col = (c & 15) * 8;
    gld_lds16(Qg + (size_t)row * (H_ * D_) + col, sQ + c * 8);
  }

  float m_i[2][4], l_i[2][4];
  f32x4 o[2][8] = {};
  #pragma unroll
  for (int i = 0; i < 2; ++i)
    #pragma unroll
    for (int r = 0; r < 4; ++r) { m_i[i][r] = -INFINITY; l_i[i][r] = 0.f; }

  const int ntile = qt * 2 + 2;
  for (int it = 0; it < ntile; ++it) {
    const int t0 = it * 64;
    #pragma unroll
    for (int r = 0; r < 4; ++r) {            // K tile 64x128
      int c = tid + r * 256;
      int row = c >> 4, col = (c & 15) * 8;
      gld_lds16(Kg + (size_t)(t0 + row) * (KV_ * D_) + col, sKP + c * 8);
    }
    #pragma unroll
    for (int r = 0; r < 4; ++r) {            // V^T tile 128x64
      int c = tid + r * 256;
      int row = c >> 3, col = (c & 7) * 8;
      gld_lds16(Vg + (size_t)row * T_ + t0 + col, sV + c * 8);
    }
    __syncthreads();                         // B1: loads drained

    // S = Q K^T (wave: 2 row-tiles x 4 col-tiles, 4 K-steps over D=128)
    f32x4 s[2][4] = {};
    #pragma unroll
    for (int kk = 0; kk < 4; ++kk) {
      bf16x8 aq[2], bk[4];
      #pragma unroll
      for (int i = 0; i < 2; ++i)
        aq[i] = *(const bf16x8*)(sQ + (wm + i * 16 + l16) * 128 + kk * 32 + quad * 8);
      #pragma unroll
      for (int j = 0; j < 4; ++j)
        bk[j] = *(const bf16x8*)(sKP + (j * 16 + l16) * 128 + kk * 32 + quad * 8);
      #pragma unroll
      for (int i = 0; i < 2; ++i)
        #pragma unroll
        for (int j = 0; j < 4; ++j)
          s[i][j] = __builtin_amdgcn_mfma_f32_16x16x32_bf16(aq[i], bk[j], s[i][j], 0, 0, 0);
    }

    if (t0 + 63 > q0 + wm) {                 // causal mask (keep col <= row)
      #pragma unroll
      for (int i = 0; i < 2; ++i) {
        int rowb = q0 + wm + i * 16 + quad * 4;
        #pragma unroll
        for (int j = 0; j < 4; ++j) {
          int colg = t0 + j * 16 + l16;
          #pragma unroll
          for (int r = 0; r < 4; ++r)
            if (colg > rowb + r) s[i][j][r] = -3.0e38f;
        }
      }
    }

    // online softmax; row stats replicated across the 16 lanes of each quad
    float alpha[2][4];
    #pragma unroll
    for (int i = 0; i < 2; ++i) {
      #pragma unroll
      for (int r = 0; r < 4; ++r) {
        float mx = fmaxf(fmaxf(s[i][0][r], s[i][1][r]), fmaxf(s[i][2][r], s[i][3][r]));
        mx = fmaxf(mx, __shfl_xor(mx, 1, 64));
        mx = fmaxf(mx, __shfl_xor(mx, 2, 64));
        mx = fmaxf(mx, __shfl_xor(mx, 4, 64));
        mx = fmaxf(mx, __shfl_xor(mx, 8, 64));
        float mnew = fmaxf(m_i[i][r], mx);
        float a = __expf(m_i[i][r] - mnew);
        m_i[i][r] = mnew; alpha[i][r] = a;
        float rs = 0.f;
        #pragma unroll
        for (int j = 0; j < 4; ++j) {
          float p = __expf(s[i][j][r] - mnew);
          s[i][j][r] = p; rs += p;
        }
        rs += __shfl_xor(rs, 1, 64);
        rs += __shfl_xor(rs, 2, 64);
        rs += __shfl_xor(rs, 4, 64);
        rs += __shfl_xor(rs, 8, 64);
        l_i[i][r] = l_i[i][r] * a + rs;
      }
    }
    #pragma unroll
    for (int i = 0; i < 2; ++i)
      #pragma unroll
      for (int j = 0; j < 8; ++j)
        #pragma unroll
        for (int r = 0; r < 4; ++r)
          o[i][j][r] *= alpha[i][r];

    __syncthreads();                         // B2: all waves done reading K before P overwrites

    // P -> LDS (C/D layout -> row-major [128][64]); each wave writes only its own rows
    #pragma unroll
    for (int i = 0; i < 2; ++i)
      #pragma unroll
      for (int j = 0; j < 4; ++j)
        #pragma unroll
        for (int r = 0; r < 4; ++r)
          sKP[(wm + i * 16 + quad * 4 + r) * 64 + j * 16 + l16] = f2b(s[i][j][r]);

    // O += P V  (A-frags read only this wave's P rows; no barrier needed)
    #pragma unroll
    for (int kk = 0; kk < 2; ++kk) {
      bf16x8 ap[2], bv[8];
      #pragma unroll
      for (int i = 0; i < 2; ++i)
        ap[i] = *(const bf16x8*)(sKP + (wm + i * 16 + l16) * 64 + kk * 32 + quad * 8);
      #pragma unroll
      for (int j = 0; j < 8; ++j)
        bv[j] = *(const bf16x8*)(sV + (j * 16 + l16) * 64 + kk * 32 + quad * 8);
      #pragma unroll
      for (int i = 0; i < 2; ++i)
        #pragma unroll
        for (int j = 0; j < 8; ++j)
          o[i][j] = __builtin_amdgcn_mfma_f32_16x16x32_bf16(ap[i], bv[j], o[i][j], 0, 0, 0);
    }
    __syncthreads();                         // B_end: done with sKP/sV before next load issue
  }

  #pragma unroll
  for (int i = 0; i < 2; ++i) {
    #pragma unroll
    for (int r = 0; r < 4; ++r) {
      float inv = 1.0f / l_i[i][r];
      int tg = q0 + wm + i * 16 + quad * 4 + r;
      unsigned short* yr = yb + (((size_t)(b * T_ + tg)) * H_ + h) * D_;
      #pragma unroll
      for (int j = 0; j < 8; ++j)
        yr[j * 16 + l16] = f2b(o[i][j][r] * inv);
    }
  }
}

extern "C" void kernel_launch(void* const* d_in, const int* in_sizes, int n_in,
                              void* d_out, int out_size, void* d_ws, size_t ws_size,
                              hipStream_t stream) {
  (void)in_sizes; (void)n_in; (void)out_size; (void)ws_size;
  const float* x  = (const float*)d_in[0];
  const float* cs = (const float*)d_in[1];
  const float* sn = (const float*)d_in[2];
  const float* Wq = (const float*)d_in[3];
  const float* Wk = (const float*)d_in[4];
  const float* Wv = (const float*)d_in[5];
  const float* Wo = (const float*)d_in[6];
  float* out = (float*)d_out;
  char* ws = (char*)d_ws;

  // workspace layout (bytes); yb aliases qraw (dead after ropenorm). total ~88MB.
  unsigned short* xb   = (unsigned short*)(ws + 0);          // 4096x2048 bf16
  unsigned short* Wqt  = (unsigned short*)(ws + 16777216);   // 2048x2048 bf16 (N x K)
  unsigned short* Wkt  = (unsigned short*)(ws + 25165824);   // 512x2048
  unsigned short* Wvt  = (unsigned short*)(ws + 27262976);   // 512x2048
  unsigned short* Wot  = (unsigned short*)(ws + 29360128);   // 2048x2048
  unsigned short* qraw = (unsigned short*)(ws + 37748736);   // (B,T,H,D) bf16
  unsigned short* kraw = (unsigned short*)(ws + 54525952);   // (B,T,KV,D)
  unsigned short* vraw = (unsigned short*)(ws + 58720256);   // (B,T,KV,D)
  unsigned short* qn   = (unsigned short*)(ws + 62914560);   // roped+normed+scaled Q
  unsigned short* kn   = (unsigned short*)(ws + 79691776);   // roped+normed K
  unsigned short* vtr  = (unsigned short*)(ws + 83886080);   // (B,KV,D,T)
  unsigned short* yb   = qraw;                               // attention output (B,T,C) bf16

  cast_bf16_k<<<dim3(8192), dim3(256), 0, stream>>>(x, xb);
  wtrans<<<dim3(64, 64), dim3(32, 8), 0, stream>>>(Wq, Wqt, 2048, 2048);
  wtrans<<<dim3(16, 64), dim3(32, 8), 0, stream>>>(Wk, Wkt, 2048, 512);
  wtrans<<<dim3(16, 64), dim3(32, 8), 0, stream>>>(Wv, Wvt, 2048, 512);
  wtrans<<<dim3(64, 64), dim3(32, 8), 0, stream>>>(Wo, Wot, 2048, 2048);
  qkv_gemm<<<dim3(24, 32), dim3(256), 0, stream>>>(xb, Wqt, Wkt, Wvt, qraw, kraw, vraw);
  ropenorm<<<dim3(16384), dim3(256), 0, stream>>>(qraw, cs, sn, qn, 16, 0.08838834764831845f);
  ropenorm<<<dim3(4096),  dim3(256), 0, stream>>>(kraw, cs, sn, kn, 4, 1.0f);
  vtrans<<<dim3(64, 4, 8), dim3(32, 8), 0, stream>>>(vraw, vtr);
  attn_kernel<<<dim3(16, 32), dim3(256), 0, stream>>>(qn, kn, vtr, yb);
  out_gemm<<<dim3(16, 32), dim3(256), 0, stream>>>(yb, Wot, out);
}

// Round 2
// 520.325 us; speedup vs baseline: 1.1292x; 1.1292x over previous
//
#include <hip/hip_runtime.h>

using bf16x8 = __attribute__((ext_vector_type(8))) short;
using f32x4  = __attribute__((ext_vector_type(4))) float;

#define B_  2
#define T_  2048
#define C_  2048
#define H_  16
#define KV_ 4
#define D_  128

__device__ __forceinline__ unsigned short f2b(float f) {
  union { float f; unsigned int u; } v; v.f = f;
  unsigned int r = v.u + 0x7fffu + ((v.u >> 16) & 1u);   // RTNE
  return (unsigned short)(r >> 16);
}
__device__ __forceinline__ float b2f(unsigned short u) {
  union { unsigned int u; float f; } v; v.u = ((unsigned int)u) << 16;
  return v.f;
}
// async global->LDS, 16B per lane; LDS dest must be lane-contiguous (wave base + lane*16)
__device__ __forceinline__ void gld_lds16(const void* g, void* l) {
  __builtin_amdgcn_global_load_lds(
      (__attribute__((address_space(1))) void*)g,
      (__attribute__((address_space(3))) void*)l, 16, 0, 0);
}

// ---------------- elementwise cast x -> bf16 ----------------
__global__ void cast_bf16_k(const float* __restrict__ in, unsigned short* __restrict__ out) {
  int i = blockIdx.x * 256 + threadIdx.x;
  float4 f = ((const float4*)in)[i];
  ushort4 u; u.x = f2b(f.x); u.y = f2b(f.y); u.z = f2b(f.z); u.w = f2b(f.w);
  ((ushort4*)out)[i] = u;
}

// ---------------- transpose-cast W (K x N fp32) -> Wt (N x K bf16) ----------------
__global__ void wtrans(const float* __restrict__ W, unsigned short* __restrict__ Wt,
                       int K, int N) {
  __shared__ float s[32][33];
  int n0 = blockIdx.x * 32, k0 = blockIdx.y * 32;
  int tx = threadIdx.x, ty = threadIdx.y;
  #pragma unroll
  for (int yy = 0; yy < 32; yy += 8)
    s[ty + yy][tx] = W[(size_t)(k0 + ty + yy) * N + n0 + tx];
  __syncthreads();
  #pragma unroll
  for (int yy = 0; yy < 32; yy += 8)
    Wt[(size_t)(n0 + ty + yy) * K + k0 + tx] = f2b(s[tx][ty + yy]);
}

// ---------------- m97-style bf16 MFMA GEMM tile: C = A(MxK) * Bt(NxK)^T ----------------
template <bool OUT_BF16>
__device__ __forceinline__ void gemm_tile(
    const unsigned short* __restrict__ A, const unsigned short* __restrict__ Bt,
    void* __restrict__ Cv, int K, int ldc, int m0, int n0b, int n0c,
    unsigned short* sA, unsigned short* sB)
{
  const int tid  = threadIdx.x;
  const int lane = tid & 63, w = tid >> 6;
  const int quad = lane >> 4, l16 = lane & 15;
  const int wm = (w >> 1) * 64, wn = (w & 1) * 64;

  f32x4 acc[4][4] = {};

  const unsigned short* Abase = A  + (size_t)m0  * K;
  const unsigned short* Bbase = Bt + (size_t)n0b * K;

  for (int k0 = 0; k0 < K; k0 += 32) {
    #pragma unroll
    for (int r = 0; r < 2; ++r) {                   // 128x32 bf16 tile = 512 chunks of 16B
      int c = tid + r * 256;
      int row = c >> 2, col = (c & 3) * 8;
      gld_lds16(Abase + (size_t)row * K + k0 + col, sA + c * 8);
      gld_lds16(Bbase + (size_t)row * K + k0 + col, sB + c * 8);
    }
    __syncthreads();                                // drains vmcnt, LDS visible
    bf16x8 af[4], bfr[4];
    #pragma unroll
    for (int i = 0; i < 4; ++i)
      af[i]  = *(const bf16x8*)(sA + (wm + i * 16 + l16) * 32 + quad * 8);
    #pragma unroll
    for (int j = 0; j < 4; ++j)
      bfr[j] = *(const bf16x8*)(sB + (wn + j * 16 + l16) * 32 + quad * 8);
    #pragma unroll
    for (int i = 0; i < 4; ++i)
      #pragma unroll
      for (int j = 0; j < 4; ++j)
        acc[i][j] = __builtin_amdgcn_mfma_f32_16x16x32_bf16(af[i], bfr[j], acc[i][j], 0, 0, 0);
    __syncthreads();                                // all waves done reading before overwrite
  }
  #pragma unroll
  for (int i = 0; i < 4; ++i) {
    #pragma unroll
    for (int r = 0; r < 4; ++r) {
      int row = m0 + wm + i * 16 + quad * 4 + r;    // C/D: row = quad*4+reg, col = lane&15
      #pragma unroll
      for (int j = 0; j < 4; ++j) {
        int col = n0c + wn + j * 16 + l16;
        float v = acc[i][j][r];
        if (OUT_BF16) ((unsigned short*)Cv)[(size_t)row * ldc + col] = f2b(v);
        else          ((float*)Cv)[(size_t)row * ldc + col] = v;
      }
    }
  }
}

// fused QKV projection: 24 n-tiles (16 Q, 4 K, 4 V) x 32 m-tiles
__global__ void qkv_gemm(const unsigned short* __restrict__ xb,
                         const unsigned short* __restrict__ Wqt,
                         const unsigned short* __restrict__ Wkt,
                         const unsigned short* __restrict__ Wvt,
                         unsigned short* q, unsigned short* k, unsigned short* v) {
  __shared__ unsigned short sA[128 * 32], sB[128 * 32];
  int nt = blockIdx.x, mt = blockIdx.y;
  const unsigned short* Bt; unsigned short* C; int n0, ldc;
  if (nt < 16)      { Bt = Wqt; C = q; n0 = nt * 128;        ldc = H_ * D_;  }
  else if (nt < 20) { Bt = Wkt; C = k; n0 = (nt - 16) * 128; ldc = KV_ * D_; }
  else              { Bt = Wvt; C = v; n0 = (nt - 20) * 128; ldc = KV_ * D_; }
  gemm_tile<true>(xb, Bt, C, C_, ldc, mt * 128, n0, n0, sA, sB);
}

__global__ void out_gemm(const unsigned short* __restrict__ yb,
                         const unsigned short* __restrict__ Wot,
                         float* __restrict__ out) {
  __shared__ unsigned short sA[128 * 32], sB[128 * 32];
  gemm_tile<false>(yb, Wot, out, C_, C_, blockIdx.y * 128, blockIdx.x * 128, blockIdx.x * 128,
                   sA, sB);
}

// ---------------- RoPE + RMSNorm: one wave per (b,t,head) row of 128 ----------------
__global__ void ropenorm(const unsigned short* __restrict__ in,
                         const float* __restrict__ cs, const float* __restrict__ sn,
                         unsigned short* __restrict__ out, int NH, float oscale) {
  int row  = blockIdx.x * 4 + (threadIdx.x >> 6);
  int lane = threadIdx.x & 63;
  int t = (row / NH) & (T_ - 1);
  const unsigned short* p = in + (size_t)row * D_;
  float t1 = b2f(p[lane]), t2 = b2f(p[lane + 64]);
  float c = cs[t * 64 + lane], s = sn[t * 64 + lane];
  float o1 = t1 * c + t2 * s;
  float o2 = t2 * c - t1 * s;
  float ss = o1 * o1 + o2 * o2;
  #pragma unroll
  for (int off = 32; off > 0; off >>= 1) ss += __shfl_xor(ss, off, 64);
  float r = rsqrtf(ss * (1.0f / 128.0f) + 1.1920929e-07f) * oscale;
  unsigned short* q = out + (size_t)row * D_;
  q[lane]      = f2b(o1 * r);
  q[lane + 64] = f2b(o2 * r);
}

// ---------------- V transpose: (B,T,KV,D) bf16 -> (B,KV,D,T) bf16 ----------------
__global__ void vtrans(const unsigned short* __restrict__ v, unsigned short* __restrict__ vt) {
  __shared__ unsigned short s[32][33];
  int t0 = blockIdx.x * 32, d0 = blockIdx.y * 32;
  int bk = blockIdx.z; int b = bk >> 2, kv = bk & 3;
  int tx = threadIdx.x, ty = threadIdx.y;
  #pragma unroll
  for (int yy = 0; yy < 32; yy += 8)
    s[ty + yy][tx] = v[(((size_t)(b * T_) + t0 + ty + yy) * KV_ + kv) * D_ + d0 + tx];
  __syncthreads();
  #pragma unroll
  for (int yy = 0; yy < 32; yy += 8)
    vt[(((size_t)(b * KV_) + kv) * D_ + d0 + ty + yy) * T_ + t0 + tx] = s[tx][ty + yy];
}

// ---------------- flash attention v2: barrier-free, register-direct fragments ----------
// Each wave owns 32 Q rows; block = 2 waves = 64 Q rows. All MFMA fragments are
// 16B-contiguous in global memory (D=128 inner dim), so Q/K/V frags load straight
// into VGPRs. S^T = K*Q^T so softmax reduces over K with only 2 cross-lane shuffles.
// P transposes C-layout -> A-layout via a per-wave private LDS slice (no barriers).
__global__ __launch_bounds__(128) void attn_kernel(
    const unsigned short* __restrict__ qb, const unsigned short* __restrict__ kb,
    const unsigned short* __restrict__ vt, unsigned short* __restrict__ yb) {
  __shared__ unsigned short sP[2 * 32 * 72];   // per-wave 32x64 P slice, stride 72 (16B-aligned rows)

  const int qt = 31 - (int)blockIdx.x;         // heavy (late) Q tiles first
  const int q0 = qt * 64;
  const int bh = blockIdx.y;
  const int b = bh >> 4, h = bh & 15, kv = h >> 2;

  const int tid = threadIdx.x;
  const int lane = tid & 63, w = tid >> 6;
  const int quad = lane >> 4, l16 = lane & 15;
  const int wm = w * 32;                       // wave's 32 Q rows within the 64-row block
  unsigned short* myP = sP + w * (32 * 72);

  const unsigned short* Qg = qb + (((size_t)(b * T_ + q0 + wm)) * H_ + h) * D_;
  const unsigned short* Kg = kb + ((size_t)(b * T_) * KV_ + kv) * D_;
  const unsigned short* Vg = vt + ((size_t)(b * KV_ + kv)) * (size_t)D_ * T_;

  // persistent Q fragments (B-operand: n = q row, k = head dim)
  bf16x8 bq[2][4];
  #pragma unroll
  for (int i = 0; i < 2; ++i)
    #pragma unroll
    for (int kk = 0; kk < 4; ++kk)
      bq[i][kk] = *(const bf16x8*)(Qg + (size_t)(i * 16 + l16) * (H_ * D_) + kk * 32 + quad * 8);

  float m_i[2] = {-INFINITY, -INFINITY}, l_i[2] = {0.f, 0.f};
  f32x4 o[2][8] = {};                          // rows q (C-layout), cols d (j*16+l16)

  const int ntile = qt + 1;
  for (int it = 0; it < ntile; ++it) {
    const int t0 = it * 64;

    // S^T = K Q^T : M = 64 k rows (4 tiles), N = 32 q cols (2 tiles)
    f32x4 sc[4][2] = {};
    #pragma unroll
    for (int kk = 0; kk < 4; ++kk) {
      bf16x8 ak[4];
      #pragma unroll
      for (int jt = 0; jt < 4; ++jt)
        ak[jt] = *(const bf16x8*)(Kg + (size_t)(t0 + jt * 16 + l16) * (KV_ * D_) + kk * 32 + quad * 8);
      #pragma unroll
      for (int jt = 0; jt < 4; ++jt)
        #pragma unroll
        for (int i = 0; i < 2; ++i)
          sc[jt][i] = __builtin_amdgcn_mfma_f32_16x16x32_bf16(ak[jt], bq[i][kk], sc[jt][i], 0, 0, 0);
    }

    if (t0 + 63 > q0 + wm) {                   // causal mask: keep k <= q
      #pragma unroll
      for (int jt = 0; jt < 4; ++jt) {
        int kg = t0 + jt * 16 + quad * 4;
        #pragma unroll
        for (int i = 0; i < 2; ++i) {
          int qg = q0 + wm + i * 16 + l16;
          #pragma unroll
          for (int r = 0; r < 4; ++r)
            if (kg + r > qg) sc[jt][i][r] = -3.0e38f;
        }
      }
    }

    // online softmax per q column (lane l16, tile i); stats replicated across quads
    #pragma unroll
    for (int i = 0; i < 2; ++i) {
      float mx = -3.0e38f;
      #pragma unroll
      for (int jt = 0; jt < 4; ++jt)
        #pragma unroll
        for (int r = 0; r < 4; ++r) mx = fmaxf(mx, sc[jt][i][r]);
      mx = fmaxf(mx, __shfl_xor(mx, 16, 64));
      mx = fmaxf(mx, __shfl_xor(mx, 32, 64));
      float mnew = fmaxf(m_i[i], mx);
      float a = __expf(m_i[i] - mnew);
      float rs = 0.f;
      #pragma unroll
      for (int jt = 0; jt < 4; ++jt)
        #pragma unroll
        for (int r = 0; r < 4; ++r) {
          float p = __expf(sc[jt][i][r] - mnew);
          sc[jt][i][r] = p; rs += p;
        }
      rs += __shfl_xor(rs, 16, 64);
      rs += __shfl_xor(rs, 32, 64);
      m_i[i] = mnew; l_i[i] = l_i[i] * a + rs;
      // alpha lives in column space (per l16); o rows are quad*4+r -> transpose via shfl
      float ar[4];
      #pragma unroll
      for (int r = 0; r < 4; ++r) ar[r] = __shfl(a, quad * 4 + r, 64);
      #pragma unroll
      for (int j = 0; j < 8; ++j)
        #pragma unroll
        for (int r = 0; r < 4; ++r) o[i][j][r] *= ar[r];
    }

    // P^T (C-layout) -> per-wave LDS row-major P [q32][k64], packed 4 k's per store
    #pragma unroll
    for (int i = 0; i < 2; ++i)
      #pragma unroll
      for (int jt = 0; jt < 4; ++jt) {
        ushort4 u;
        u.x = f2b(sc[jt][i][0]); u.y = f2b(sc[jt][i][1]);
        u.z = f2b(sc[jt][i][2]); u.w = f2b(sc[jt][i][3]);
        *(ushort4*)(myP + (i * 16 + l16) * 72 + jt * 16 + quad * 4) = u;
      }

    // O += P V : A-frags from private LDS, V^T B-frags direct from global
    #pragma unroll
    for (int kk2 = 0; kk2 < 2; ++kk2) {
      bf16x8 ap[2], bv[8];
      #pragma unroll
      for (int i = 0; i < 2; ++i)
        ap[i] = *(const bf16x8*)(myP + (i * 16 + l16) * 72 + kk2 * 32 + quad * 8);
      #pragma unroll
      for (int j = 0; j < 8; ++j)
        bv[j] = *(const bf16x8*)(Vg + (size_t)(j * 16 + l16) * T_ + t0 + kk2 * 32 + quad * 8);
      #pragma unroll
      for (int i = 0; i < 2; ++i)
        #pragma unroll
        for (int j = 0; j < 8; ++j)
          o[i][j] = __builtin_amdgcn_mfma_f32_16x16x32_bf16(ap[i], bv[j], o[i][j], 0, 0, 0);
    }
  }

  #pragma unroll
  for (int i = 0; i < 2; ++i) {
    float linv = 1.0f / l_i[i];
    float lr[4];
    #pragma unroll
    for (int r = 0; r < 4; ++r) lr[r] = __shfl(linv, quad * 4 + r, 64);
    #pragma unroll
    for (int r = 0; r < 4; ++r) {
      int tg = q0 + wm + i * 16 + quad * 4 + r;
      unsigned short* yr = yb + (((size_t)(b * T_ + tg)) * H_ + h) * D_;
      #pragma unroll
      for (int j = 0; j < 8; ++j)
        yr[j * 16 + l16] = f2b(o[i][j][r] * lr[r]);
    }
  }
}

extern "C" void kernel_launch(void* const* d_in, const int* in_sizes, int n_in,
                              void* d_out, int out_size, void* d_ws, size_t ws_size,
                              hipStream_t stream) {
  (void)in_sizes; (void)n_in; (void)out_size; (void)ws_size;
  const float* x  = (const float*)d_in[0];
  const float* cs = (const float*)d_in[1];
  const float* sn = (const float*)d_in[2];
  const float* Wq = (const float*)d_in[3];
  const float* Wk = (const float*)d_in[4];
  const float* Wv = (const float*)d_in[5];
  const float* Wo = (const float*)d_in[6];
  float* out = (float*)d_out;
  char* ws = (char*)d_ws;

  // workspace layout (bytes); yb aliases qraw (dead after ropenorm). total ~88MB.
  unsigned short* xb   = (unsigned short*)(ws + 0);          // 4096x2048 bf16
  unsigned short* Wqt  = (unsigned short*)(ws + 16777216);   // 2048x2048 bf16 (N x K)
  unsigned short* Wkt  = (unsigned short*)(ws + 25165824);   // 512x2048
  unsigned short* Wvt  = (unsigned short*)(ws + 27262976);   // 512x2048
  unsigned short* Wot  = (unsigned short*)(ws + 29360128);   // 2048x2048
  unsigned short* qraw = (unsigned short*)(ws + 37748736);   // (B,T,H,D) bf16
  unsigned short* kraw = (unsigned short*)(ws + 54525952);   // (B,T,KV,D)
  unsigned short* vraw = (unsigned short*)(ws + 58720256);   // (B,T,KV,D)
  unsigned short* qn   = (unsigned short*)(ws + 62914560);   // roped+normed+scaled Q
  unsigned short* kn   = (unsigned short*)(ws + 79691776);   // roped+normed K
  unsigned short* vtr  = (unsigned short*)(ws + 83886080);   // (B,KV,D,T)
  unsigned short* yb   = qraw;                               // attention output (B,T,C) bf16

  cast_bf16_k<<<dim3(8192), dim3(256), 0, stream>>>(x, xb);
  wtrans<<<dim3(64, 64), dim3(32, 8), 0, stream>>>(Wq, Wqt, 2048, 2048);
  wtrans<<<dim3(16, 64), dim3(32, 8), 0, stream>>>(Wk, Wkt, 2048, 512);
  wtrans<<<dim3(16, 64), dim3(32, 8), 0, stream>>>(Wv, Wvt, 2048, 512);
  wtrans<<<dim3(64, 64), dim3(32, 8), 0, stream>>>(Wo, Wot, 2048, 2048);
  qkv_gemm<<<dim3(24, 32), dim3(256), 0, stream>>>(xb, Wqt, Wkt, Wvt, qraw, kraw, vraw);
  ropenorm<<<dim3(16384), dim3(256), 0, stream>>>(qraw, cs, sn, qn, 16, 0.08838834764831845f);
  ropenorm<<<dim3(4096),  dim3(256), 0, stream>>>(kraw, cs, sn, kn, 4, 1.0f);
  vtrans<<<dim3(64, 4, 8), dim3(32, 8), 0, stream>>>(vraw, vtr);
  attn_kernel<<<dim3(32, 32), dim3(128), 0, stream>>>(qn, kn, vtr, yb);
  out_gemm<<<dim3(16, 32), dim3(256), 0, stream>>>(yb, Wot, out);
}

// Round 3
// 409.181 us; speedup vs baseline: 1.4359x; 1.2716x over previous
//
#include <hip/hip_runtime.h>

using bf16x8 = __attribute__((ext_vector_type(8))) short;
using f32x4  = __attribute__((ext_vector_type(4))) float;

#define B_  2
#define T_  2048
#define C_  2048
#define H_  16
#define KV_ 4
#define D_  128

__device__ __forceinline__ unsigned short f2b(float f) {
  union { float f; unsigned int u; } v; v.f = f;
  unsigned int r = v.u + 0x7fffu + ((v.u >> 16) & 1u);   // RTNE
  return (unsigned short)(r >> 16);
}
__device__ __forceinline__ float b2f(unsigned short u) {
  union { unsigned int u; float f; } v; v.u = ((unsigned int)u) << 16;
  return v.f;
}
// async global->LDS, 16B per lane; LDS dest must be lane-contiguous (wave base + lane*16)
__device__ __forceinline__ void gld_lds16(const void* g, void* l) {
  __builtin_amdgcn_global_load_lds(
      (__attribute__((address_space(1))) void*)g,
      (__attribute__((address_space(3))) void*)l, 16, 0, 0);
}

// ---------------- elementwise cast x -> bf16 ----------------
__global__ void cast_bf16_k(const float* __restrict__ in, unsigned short* __restrict__ out) {
  int i = blockIdx.x * 256 + threadIdx.x;
  float4 f = ((const float4*)in)[i];
  ushort4 u; u.x = f2b(f.x); u.y = f2b(f.y); u.z = f2b(f.z); u.w = f2b(f.w);
  ((ushort4*)out)[i] = u;
}

// ---------------- transpose-cast W (K x N fp32) -> Wt (N x K bf16) ----------------
__global__ void wtrans(const float* __restrict__ W, unsigned short* __restrict__ Wt,
                       int K, int N) {
  __shared__ float s[32][33];
  int n0 = blockIdx.x * 32, k0 = blockIdx.y * 32;
  int tx = threadIdx.x, ty = threadIdx.y;
  #pragma unroll
  for (int yy = 0; yy < 32; yy += 8)
    s[ty + yy][tx] = W[(size_t)(k0 + ty + yy) * N + n0 + tx];
  __syncthreads();
  #pragma unroll
  for (int yy = 0; yy < 32; yy += 8)
    Wt[(size_t)(n0 + ty + yy) * K + k0 + tx] = f2b(s[tx][ty + yy]);
}

// ---------------- m97-style bf16 MFMA GEMM tile: C = A(MxK) * Bt(NxK)^T ----------------
template <bool OUT_BF16>
__device__ __forceinline__ void gemm_tile(
    const unsigned short* __restrict__ A, const unsigned short* __restrict__ Bt,
    void* __restrict__ Cv, int K, int ldc, int m0, int n0b, int n0c,
    unsigned short* sA, unsigned short* sB)
{
  const int tid  = threadIdx.x;
  const int lane = tid & 63, w = tid >> 6;
  const int quad = lane >> 4, l16 = lane & 15;
  const int wm = (w >> 1) * 64, wn = (w & 1) * 64;

  f32x4 acc[4][4] = {};

  const unsigned short* Abase = A  + (size_t)m0  * K;
  const unsigned short* Bbase = Bt + (size_t)n0b * K;

  for (int k0 = 0; k0 < K; k0 += 32) {
    #pragma unroll
    for (int r = 0; r < 2; ++r) {                   // 128x32 bf16 tile = 512 chunks of 16B
      int c = tid + r * 256;
      int row = c >> 2, col = (c & 3) * 8;
      gld_lds16(Abase + (size_t)row * K + k0 + col, sA + c * 8);
      gld_lds16(Bbase + (size_t)row * K + k0 + col, sB + c * 8);
    }
    __syncthreads();                                // drains vmcnt, LDS visible
    bf16x8 af[4], bfr[4];
    #pragma unroll
    for (int i = 0; i < 4; ++i)
      af[i]  = *(const bf16x8*)(sA + (wm + i * 16 + l16) * 32 + quad * 8);
    #pragma unroll
    for (int j = 0; j < 4; ++j)
      bfr[j] = *(const bf16x8*)(sB + (wn + j * 16 + l16) * 32 + quad * 8);
    #pragma unroll
    for (int i = 0; i < 4; ++i)
      #pragma unroll
      for (int j = 0; j < 4; ++j)
        acc[i][j] = __builtin_amdgcn_mfma_f32_16x16x32_bf16(af[i], bfr[j], acc[i][j], 0, 0, 0);
    __syncthreads();                                // all waves done reading before overwrite
  }
  #pragma unroll
  for (int i = 0; i < 4; ++i) {
    #pragma unroll
    for (int r = 0; r < 4; ++r) {
      int row = m0 + wm + i * 16 + quad * 4 + r;    // C/D: row = quad*4+reg, col = lane&15
      #pragma unroll
      for (int j = 0; j < 4; ++j) {
        int col = n0c + wn + j * 16 + l16;
        float v = acc[i][j][r];
        if (OUT_BF16) ((unsigned short*)Cv)[(size_t)row * ldc + col] = f2b(v);
        else          ((float*)Cv)[(size_t)row * ldc + col] = v;
      }
    }
  }
}

// fused QKV projection: 24 n-tiles (16 Q, 4 K, 4 V) x 32 m-tiles
__global__ void qkv_gemm(const unsigned short* __restrict__ xb,
                         const unsigned short* __restrict__ Wqt,
                         const unsigned short* __restrict__ Wkt,
                         const unsigned short* __restrict__ Wvt,
                         unsigned short* q, unsigned short* k, unsigned short* v) {
  __shared__ unsigned short sA[128 * 32], sB[128 * 32];
  int nt = blockIdx.x, mt = blockIdx.y;
  const unsigned short* Bt; unsigned short* C; int n0, ldc;
  if (nt < 16)      { Bt = Wqt; C = q; n0 = nt * 128;        ldc = H_ * D_;  }
  else if (nt < 20) { Bt = Wkt; C = k; n0 = (nt - 16) * 128; ldc = KV_ * D_; }
  else              { Bt = Wvt; C = v; n0 = (nt - 20) * 128; ldc = KV_ * D_; }
  gemm_tile<true>(xb, Bt, C, C_, ldc, mt * 128, n0, n0, sA, sB);
}

__global__ void out_gemm(const unsigned short* __restrict__ yb,
                         const unsigned short* __restrict__ Wot,
                         float* __restrict__ out) {
  __shared__ unsigned short sA[128 * 32], sB[128 * 32];
  gemm_tile<false>(yb, Wot, out, C_, C_, blockIdx.y * 128, blockIdx.x * 128, blockIdx.x * 128,
                   sA, sB);
}

// ---------------- RoPE + RMSNorm: one wave per (b,t,head) row of 128 ----------------
// KFRAG=false: row-major output (Q). KFRAG=true: MFMA-fragment-order output (K):
// per (b,kv): [t16 (128 tiles)][f = d>>3 (16)][t&15 (16)][d&7 (8)]  (t16-tile = 2048 shorts)
template <bool KFRAG>
__global__ void ropenorm(const unsigned short* __restrict__ in,
                         const float* __restrict__ cs, const float* __restrict__ sn,
                         unsigned short* __restrict__ out, int NH, float oscale) {
  int row  = blockIdx.x * 4 + (threadIdx.x >> 6);
  int lane = threadIdx.x & 63;
  int t = (row / NH) & (T_ - 1);
  const unsigned short* p = in + (size_t)row * D_;
  float t1 = b2f(p[lane]), t2 = b2f(p[lane + 64]);
  float c = cs[t * 64 + lane], s = sn[t * 64 + lane];
  float o1 = t1 * c + t2 * s;
  float o2 = t2 * c - t1 * s;
  float ss = o1 * o1 + o2 * o2;
  #pragma unroll
  for (int off = 32; off > 0; off >>= 1) ss += __shfl_xor(ss, off, 64);
  float r = rsqrtf(ss * (1.0f / 128.0f) + 1.1920929e-07f) * oscale;
  if (!KFRAG) {
    unsigned short* q = out + (size_t)row * D_;
    q[lane]      = f2b(o1 * r);
    q[lane + 64] = f2b(o2 * r);
  } else {
    int b  = row >> 13;                      // row = (b*T + t)*KV + kv
    int kv = row & 3;
    size_t base = ((size_t)((b * KV_ + kv) * 128 + (t >> 4))) * 2048 + (size_t)(t & 15) * 8;
    out[base + (size_t)(lane >> 3) * 128 + (lane & 7)]        = f2b(o1 * r);
    out[base + (size_t)(8 + (lane >> 3)) * 128 + (lane & 7)]  = f2b(o2 * r);
  }
}

// ---------------- V repack: (B,T,KV,D) bf16 -> fragment order for PV B-operand ---------
// per (b,kv): [it (32 tiles of 64 t)][dt = d>>4 (8)][f = (t&63)>>3 (8)][d&15 (16)][t&7 (8)]
__global__ void vfrag_k(const unsigned short* __restrict__ v, unsigned short* __restrict__ vf) {
  int it = blockIdx.x;
  int b = blockIdx.y >> 2, kv = blockIdx.y & 3;
  int d = threadIdx.x, ty = threadIdx.y;
  int t0 = it * 64;
  size_t obase = ((size_t)((b * KV_ + kv) * 32 + it)) * 8192
               + (size_t)(d >> 4) * 1024 + (size_t)(d & 15) * 8;
  #pragma unroll
  for (int tcg = 0; tcg < 4; ++tcg) {
    int tc = ty * 4 + tcg;                   // f chunk 0..7
    unsigned short val[8];
    #pragma unroll
    for (int e = 0; e < 8; ++e)              // coalesced: 128 lanes contiguous in d
      val[e] = v[(((size_t)(b * T_) + t0 + tc * 8 + e) * KV_ + kv) * D_ + d];
    ushort4 u0 = {val[0], val[1], val[2], val[3]};
    ushort4 u1 = {val[4], val[5], val[6], val[7]};
    *(ushort4*)(vf + obase + (size_t)tc * 128)     = u0;
    *(ushort4*)(vf + obase + (size_t)tc * 128 + 4) = u1;
  }
}

// ---------------- flash attention v3: frag-swizzled LDS staging, conflict-free ---------
// Block = 4 waves, 128 Q rows (wave w owns rows wm=w*32). K/V tiles staged coalesced via
// global_load_lds from pre-swizzled global layouts; ds_read_b128 frag reads are lane-
// contiguous (2 lanes/bank = free). S^T = K*Q^T for cheap softmax; P via private LDS.
__global__ __launch_bounds__(256) void attn_kernel(
    const unsigned short* __restrict__ qb, const unsigned short* __restrict__ kf,
    const unsigned short* __restrict__ vf, unsigned short* __restrict__ yb) {
  __shared__ unsigned short sK[8192];          // 64x128 K tile, frag order (16 KB)
  __shared__ unsigned short sV[8192];          // 128x64 V^T tile, frag order (16 KB)
  __shared__ unsigned short sP[4 * 32 * 72];   // per-wave P slice (18 KB)

  const int qt = 15 - (int)blockIdx.x;         // heavy (late) Q tiles first
  const int q0 = qt * 128;
  const int bh = blockIdx.y;
  const int b = bh >> 4, h = bh & 15, kv = h >> 2;

  const int tid = threadIdx.x;
  const int lane = tid & 63, w = tid >> 6;
  const int quad = lane >> 4, l16 = lane & 15;
  const int wm = w * 32;
  unsigned short* myP = sP + w * (32 * 72);

  const unsigned short* Qg = qb + (((size_t)(b * T_ + q0 + wm)) * H_ + h) * D_;
  const unsigned short* Kf = kf + (size_t)(b * KV_ + kv) * 128 * 2048;
  const unsigned short* Vf = vf + (size_t)(b * KV_ + kv) * 32 * 8192;

  // persistent Q fragments (B-operand: n = q row, k = head dim)
  bf16x8 bq[2][4];
  #pragma unroll
  for (int i = 0; i < 2; ++i)
    #pragma unroll
    for (int kk = 0; kk < 4; ++kk)
      bq[i][kk] = *(const bf16x8*)(Qg + (size_t)(i * 16 + l16) * (H_ * D_) + kk * 32 + quad * 8);

  float m_i[2] = {-INFINITY, -INFINITY}, l_i[2] = {0.f, 0.f};
  f32x4 o[2][8] = {};                          // rows q (C-layout), cols d

  const int ntile = qt * 2 + 2;
  for (int it = 0; it < ntile; ++it) {
    const int t0 = it * 64;
    const unsigned short* Ksrc = Kf + (size_t)(t0 >> 4) * 2048;
    const unsigned short* Vsrc = Vf + (size_t)it * 8192;
    #pragma unroll
    for (int r = 0; r < 4; ++r) {              // 1024 chunks of 16B each, fully coalesced
      int c = tid + r * 256;
      gld_lds16(Ksrc + (size_t)c * 8, sK + c * 8);
      gld_lds16(Vsrc + (size_t)c * 8, sV + c * 8);
    }
    __syncthreads();                           // B1: staging visible

    if (t0 <= q0 + wm + 31) {                  // skip compute on fully-masked tiles
      // S^T = K Q^T : 64 k rows (4 tiles) x 32 q cols (2 tiles)
      f32x4 sc[4][2] = {};
      #pragma unroll
      for (int kk = 0; kk < 4; ++kk) {
        bf16x8 ak[4];
        #pragma unroll
        for (int jt = 0; jt < 4; ++jt)
          ak[jt] = *(const bf16x8*)(sK + jt * 2048 + (kk * 4 + quad) * 128 + l16 * 8);
        #pragma unroll
        for (int jt = 0; jt < 4; ++jt)
          #pragma unroll
          for (int i = 0; i < 2; ++i)
            sc[jt][i] = __builtin_amdgcn_mfma_f32_16x16x32_bf16(ak[jt], bq[i][kk], sc[jt][i], 0, 0, 0);
      }

      if (t0 + 63 > q0 + wm) {                 // causal mask: keep k <= q
        #pragma unroll
        for (int jt = 0; jt < 4; ++jt) {
          int kg = t0 + jt * 16 + quad * 4;
          #pragma unroll
          for (int i = 0; i < 2; ++i) {
            int qg = q0 + wm + i * 16 + l16;
            #pragma unroll
            for (int r = 0; r < 4; ++r)
              if (kg + r > qg) sc[jt][i][r] = -3.0e38f;
          }
        }
      }

      // online softmax per q column; stats replicated across quads (2 shuffles each)
      #pragma unroll
      for (int i = 0; i < 2; ++i) {
        float mx = -3.0e38f;
        #pragma unroll
        for (int jt = 0; jt < 4; ++jt)
          #pragma unroll
          for (int r = 0; r < 4; ++r) mx = fmaxf(mx, sc[jt][i][r]);
        mx = fmaxf(mx, __shfl_xor(mx, 16, 64));
        mx = fmaxf(mx, __shfl_xor(mx, 32, 64));
        float mnew = fmaxf(m_i[i], mx);
        float a = __expf(m_i[i] - mnew);
        float rs = 0.f;
        #pragma unroll
        for (int jt = 0; jt < 4; ++jt)
          #pragma unroll
          for (int r = 0; r < 4; ++r) {
            float p = __expf(sc[jt][i][r] - mnew);
            sc[jt][i][r] = p; rs += p;
          }
        rs += __shfl_xor(rs, 16, 64);
        rs += __shfl_xor(rs, 32, 64);
        m_i[i] = mnew; l_i[i] = l_i[i] * a + rs;
        float ar[4];
        #pragma unroll
        for (int r = 0; r < 4; ++r) ar[r] = __shfl(a, quad * 4 + r, 64);
        #pragma unroll
        for (int j = 0; j < 8; ++j)
          #pragma unroll
          for (int r = 0; r < 4; ++r) o[i][j][r] *= ar[r];
      }

      // P^T (C-layout) -> per-wave LDS row-major P [q32][k64]
      #pragma unroll
      for (int i = 0; i < 2; ++i)
        #pragma unroll
        for (int jt = 0; jt < 4; ++jt) {
          ushort4 u;
          u.x = f2b(sc[jt][i][0]); u.y = f2b(sc[jt][i][1]);
          u.z = f2b(sc[jt][i][2]); u.w = f2b(sc[jt][i][3]);
          *(ushort4*)(myP + (i * 16 + l16) * 72 + jt * 16 + quad * 4) = u;
        }

      // O += P V : A from private LDS, B from frag-order sV (conflict-free)
      #pragma unroll
      for (int kk2 = 0; kk2 < 2; ++kk2) {
        bf16x8 ap[2], bv[8];
        #pragma unroll
        for (int i = 0; i < 2; ++i)
          ap[i] = *(const bf16x8*)(myP + (i * 16 + l16) * 72 + kk2 * 32 + quad * 8);
        #pragma unroll
        for (int j = 0; j < 8; ++j)
          bv[j] = *(const bf16x8*)(sV + j * 1024 + (kk2 * 4 + quad) * 128 + l16 * 8);
        #pragma unroll
        for (int i = 0; i < 2; ++i)
          #pragma unroll
          for (int j = 0; j < 8; ++j)
            o[i][j] = __builtin_amdgcn_mfma_f32_16x16x32_bf16(ap[i], bv[j], o[i][j], 0, 0, 0);
      }
    }
    __syncthreads();                           // B2: done reading before next staging
  }

  #pragma unroll
  for (int i = 0; i < 2; ++i) {
    float linv = 1.0f / l_i[i];
    float lr[4];
    #pragma unroll
    for (int r = 0; r < 4; ++r) lr[r] = __shfl(linv, quad * 4 + r, 64);
    #pragma unroll
    for (int r = 0; r < 4; ++r) {
      int tg = q0 + wm + i * 16 + quad * 4 + r;
      unsigned short* yr = yb + (((size_t)(b * T_ + tg)) * H_ + h) * D_;
      #pragma unroll
      for (int j = 0; j < 8; ++j)
        yr[j * 16 + l16] = f2b(o[i][j][r] * lr[r]);
    }
  }
}

extern "C" void kernel_launch(void* const* d_in, const int* in_sizes, int n_in,
                              void* d_out, int out_size, void* d_ws, size_t ws_size,
                              hipStream_t stream) {
  (void)in_sizes; (void)n_in; (void)out_size; (void)ws_size;
  const float* x  = (const float*)d_in[0];
  const float* cs = (const float*)d_in[1];
  const float* sn = (const float*)d_in[2];
  const float* Wq = (const float*)d_in[3];
  const float* Wk = (const float*)d_in[4];
  const float* Wv = (const float*)d_in[5];
  const float* Wo = (const float*)d_in[6];
  float* out = (float*)d_out;
  char* ws = (char*)d_ws;

  // workspace layout (bytes); yb aliases qraw (dead after ropenorm). total ~88MB.
  unsigned short* xb   = (unsigned short*)(ws + 0);          // 4096x2048 bf16
  unsigned short* Wqt  = (unsigned short*)(ws + 16777216);   // 2048x2048 bf16 (N x K)
  unsigned short* Wkt  = (unsigned short*)(ws + 25165824);   // 512x2048
  unsigned short* Wvt  = (unsigned short*)(ws + 27262976);   // 512x2048
  unsigned short* Wot  = (unsigned short*)(ws + 29360128);   // 2048x2048
  unsigned short* qraw = (unsigned short*)(ws + 37748736);   // (B,T,H,D) bf16
  unsigned short* kraw = (unsigned short*)(ws + 54525952);   // (B,T,KV,D)
  unsigned short* vraw = (unsigned short*)(ws + 58720256);   // (B,T,KV,D)
  unsigned short* qn   = (unsigned short*)(ws + 62914560);   // roped+normed+scaled Q (row-major)
  unsigned short* kfr  = (unsigned short*)(ws + 79691776);   // roped+normed K, frag order
  unsigned short* vfr  = (unsigned short*)(ws + 83886080);   // V, frag order
  unsigned short* yb   = qraw;                               // attention output (B,T,C) bf16

  cast_bf16_k<<<dim3(8192), dim3(256), 0, stream>>>(x, xb);
  wtrans<<<dim3(64, 64), dim3(32, 8), 0, stream>>>(Wq, Wqt, 2048, 2048);
  wtrans<<<dim3(16, 64), dim3(32, 8), 0, stream>>>(Wk, Wkt, 2048, 512);
  wtrans<<<dim3(16, 64), dim3(32, 8), 0, stream>>>(Wv, Wvt, 2048, 512);
  wtrans<<<dim3(64, 64), dim3(32, 8), 0, stream>>>(Wo, Wot, 2048, 2048);
  qkv_gemm<<<dim3(24, 32), dim3(256), 0, stream>>>(xb, Wqt, Wkt, Wvt, qraw, kraw, vraw);
  ropenorm<false><<<dim3(16384), dim3(256), 0, stream>>>(qraw, cs, sn, qn, 16, 0.08838834764831845f);
  ropenorm<true><<<dim3(4096),  dim3(256), 0, stream>>>(kraw, cs, sn, kfr, 4, 1.0f);
  vfrag_k<<<dim3(32, 8), dim3(128, 2), 0, stream>>>(vraw, vfr);
  attn_kernel<<<dim3(16, 32), dim3(256), 0, stream>>>(qn, kfr, vfr, yb);
  out_gemm<<<dim3(16, 32), dim3(256), 0, stream>>>(yb, Wot, out);
}